// Round 1
// baseline (2716.822 us; speedup 1.0000x reference)
//
#include <hip/hip_runtime.h>
#include <cstddef>

#define NSEQ 20480
#define EPSf 1e-7f
#define MAXN 0.99999f   // (1 - 1e-5)/sqrt(c), c=1

// ---------------- block-wide sum (256 threads), f64 accumulate ----------------
__device__ __forceinline__ float block_sum_d(double v, double* red) {
#pragma unroll
  for (int off = 32; off > 0; off >>= 1) v += __shfl_down(v, off);
  const int wid = threadIdx.x >> 6;
  const int lane = threadIdx.x & 63;
  if (lane == 0) red[wid] = v;
  __syncthreads();
  double s = (red[0] + red[1]) + (red[2] + red[3]);
  __syncthreads();
  return (float)s;
}

// ---------------- init: fold + embed + expmap0 + initial velocity ----------------
// one block per sequence (sidx = c*4096 + b*64 + f), 256 threads (one per dim d)
__global__ __launch_bounds__(256) void init_kernel(
    const float* __restrict__ trend, const float* __restrict__ coarse,
    const float* __restrict__ fine, const float* __restrict__ resid,
    const float* __restrict__ W_emb, const float* __restrict__ b_emb,
    float* __restrict__ U, float* __restrict__ ZL, float* __restrict__ VO)
{
  __shared__ float seg[336];
  __shared__ float zbuf[14][256];
  __shared__ float zn2[14];
  __shared__ double red[4];
  const int sidx = blockIdx.x;
  const int c = sidx >> 12;
  const int bf = sidx & 4095;
  const int b = bf >> 6, f = bf & 63;
  const int d = threadIdx.x;

  for (int l = d; l < 336; l += 256) {
    size_t idx = ((size_t)b * 336 + l) * 64 + f;
    float v;
    if (c == 0)      v = trend[idx] + coarse[idx] + fine[idx] + resid[idx];
    else if (c == 1) v = trend[idx];
    else if (c == 2) v = coarse[idx];
    else if (c == 3) v = fine[idx];
    else             v = resid[idx];
    seg[l] = v;
  }
  __syncthreads();

  // embeddings: z[s] = project(tanh(|e|)*e/|e|), e = tanh(seg_s @ W_emb + b_emb)
  for (int s = 0; s < 14; ++s) {
    float acc = b_emb[d];
#pragma unroll
    for (int g = 0; g < 24; ++g) acc = fmaf(seg[s * 24 + g], W_emb[g * 256 + d], acc);
    float e = tanhf(acc);
    float vn2 = block_sum_d((double)e * (double)e, red);
    float vn = sqrtf(fmaxf(vn2, 1e-14f));
    float pre = tanhf(vn) * e / vn;
    float n2 = block_sum_d((double)pre * (double)pre, red);
    float n = sqrtf(fmaxf(n2, 1e-14f));
    float z = (n > MAXN) ? pre * (MAXN / n) : pre;
    zbuf[s][d] = z;
    float zz2 = block_sum_d((double)z * (double)z, red);
    if (d == 0) zn2[s] = zz2;
  }
  __syncthreads();

  // decay weights: w[t] = 0.9^(12-t) / sum
  float wsum = 0.f;
#pragma unroll
  for (int t = 0; t < 13; ++t) wsum += powf(0.9f, (float)(12 - t));

  // vlog over original pairs; vel = sum w[t]*vlog[t]; store dropped pairs t<3
  float vel = 0.f;
  for (int t = 0; t < 13; ++t) {
    float xd = zbuf[t][d], yd = zbuf[t + 1][d];
    float x2 = zn2[t], y2 = zn2[t + 1];
    float xy = block_sum_d((double)xd * (double)yd, red);
    float mxy = -xy;                       // (-x)·y
    float num = (1.f + 2.f * mxy + y2) * (-xd) + (1.f - x2) * yd;
    float den = fmaxf(1.f + 2.f * mxy + x2 * y2, 1e-15f);
    float wd = num / den;
    float wn2 = block_sum_d((double)wd * (double)wd, red);
    float wn = sqrtf(fmaxf(wn2, 1e-14f));
    float lam = 2.f / fmaxf(1.f - x2, EPSf);
    float vl = (2.f / lam) * atanhf(fminf(wn, 1.f - 1e-6f)) * wd / wn;
    float wt = powf(0.9f, (float)(12 - t)) / wsum;
    vel = fmaf(wt, vl, vel);
    if (t < 3) VO[(size_t)t * NSEQ * 256 + (size_t)sidx * 256 + d] = vl;
  }

  // U = [logmap0(z13), vel]; ZL = z13
  float x13 = zbuf[13][d];
  float yn = sqrtf(fmaxf(zn2[13], 1e-14f));
  float g = atanhf(fminf(yn, 1.f - 1e-6f)) * x13 / yn;
  U[(size_t)sidx * 512 + d] = g;
  U[(size_t)sidx * 512 + 256 + d] = vel;
  ZL[(size_t)sidx * 256 + d] = x13;
}

// ---------------- f32 tiled GEMM: C(M x N) = epi(A(M x K) @ B(K x N) + bias) ----------------
// block tile 128x64, BK=16, 256 threads, 8x4 micro-tile. EPI: 0 none, 1 tanh, 2 relu
template <int EPI>
__global__ __launch_bounds__(256) void gemm_f32(
    const float* __restrict__ A, int lda,
    const float* __restrict__ B, int ldb,
    const float* __restrict__ bias,
    float* __restrict__ C, int ldc, int K)
{
  __shared__ float As[16][128];
  __shared__ float Bs[16][64];
  const int tid = threadIdx.x;
  const int row0 = blockIdx.x * 128;
  const int col0 = blockIdx.y * 64;
  const int am = tid >> 1;
  const int ak = (tid & 1) * 8;
  const int bk = tid >> 4;
  const int bn = (tid & 15) * 4;
  const int tx = tid & 15, ty = tid >> 4;
  float acc[8][4];
#pragma unroll
  for (int i = 0; i < 8; ++i)
#pragma unroll
    for (int j = 0; j < 4; ++j) acc[i][j] = 0.f;

  for (int k0 = 0; k0 < K; k0 += 16) {
    float4 a0 = *(const float4*)&A[(size_t)(row0 + am) * lda + k0 + ak];
    float4 a1 = *(const float4*)&A[(size_t)(row0 + am) * lda + k0 + ak + 4];
    float4 bv = *(const float4*)&B[(size_t)(k0 + bk) * ldb + col0 + bn];
    As[ak + 0][am] = a0.x; As[ak + 1][am] = a0.y; As[ak + 2][am] = a0.z; As[ak + 3][am] = a0.w;
    As[ak + 4][am] = a1.x; As[ak + 5][am] = a1.y; As[ak + 6][am] = a1.z; As[ak + 7][am] = a1.w;
    *(float4*)&Bs[bk][bn] = bv;
    __syncthreads();
#pragma unroll
    for (int kk = 0; kk < 16; ++kk) {
      float4 av0 = *(const float4*)&As[kk][ty * 8];
      float4 av1 = *(const float4*)&As[kk][ty * 8 + 4];
      float4 bvv = *(const float4*)&Bs[kk][tx * 4];
      float ar[8] = {av0.x, av0.y, av0.z, av0.w, av1.x, av1.y, av1.z, av1.w};
      float br[4] = {bvv.x, bvv.y, bvv.z, bvv.w};
#pragma unroll
      for (int i = 0; i < 8; ++i)
#pragma unroll
        for (int j = 0; j < 4; ++j) acc[i][j] = fmaf(ar[i], br[j], acc[i][j]);
    }
    __syncthreads();
  }
#pragma unroll
  for (int i = 0; i < 8; ++i) {
    const int row = row0 + ty * 8 + i;
    float t0[4];
#pragma unroll
    for (int j = 0; j < 4; ++j) {
      float vv = acc[i][j] + bias[col0 + tx * 4 + j];
      if (EPI == 1) vv = tanhf(vv);
      else if (EPI == 2) vv = fmaxf(vv, 0.f);
      t0[j] = vv;
    }
    float4 o = {t0[0], t0[1], t0[2], t0[3]};
    *(float4*)&C[(size_t)row * ldc + col0 + tx * 4] = o;
  }
}

// ---------------- per-sequence step: expmap + project + logmap + vel update ----------------
__global__ __launch_bounds__(256) void step_kernel(
    const float* __restrict__ V, float* __restrict__ U,
    float* __restrict__ ZL, const float* __restrict__ VOk, int k)
{
  __shared__ double red[4];
  const int sidx = blockIdx.x;
  const int d = threadIdx.x;
  float x = ZL[(size_t)sidx * 256 + d];
  float v = V[(size_t)sidx * 256 + d];
  float x2 = block_sum_d((double)x * (double)x, red);
  float vn2 = block_sum_d((double)v * (double)v, red);
  float vn = sqrtf(fmaxf(vn2, 1e-14f));
  float lam = 2.f / fmaxf(1.f - x2, EPSf);
  float th = tanhf(lam * vn * 0.5f);
  float sec = th * v / vn;
  float y2 = block_sum_d((double)sec * (double)sec, red);
  float xy = block_sum_d((double)x * (double)sec, red);
  float num = (1.f + 2.f * xy + y2) * x + (1.f - x2) * sec;
  float den = fmaxf(1.f + 2.f * xy + x2 * y2, 1e-15f);
  float zn = num / den;
  float n2 = block_sum_d((double)zn * (double)zn, red);
  float n = sqrtf(fmaxf(n2, 1e-14f));
  if (n > MAXN) zn = zn * (MAXN / n);
  ZL[(size_t)sidx * 256 + d] = zn;

  // post-projection norm, shared by logmap (y2) and logmap0 (yn)
  float y2n = block_sum_d((double)zn * (double)zn, red);
  float xy2 = block_sum_d((double)x * (double)zn, red);
  float ynn = sqrtf(fmaxf(y2n, 1e-14f));
  float g = atanhf(fminf(ynn, 1.f - 1e-6f)) * zn / ynn;
  U[(size_t)sidx * 512 + d] = g;

  if (k < 3) {
    float num2 = (1.f - 2.f * xy2 + y2n) * (-x) + (1.f - x2) * zn;
    float den2 = fmaxf(1.f - 2.f * xy2 + x2 * y2n, 1e-15f);
    float wd = num2 / den2;
    float wn2 = block_sum_d((double)wd * (double)wd, red);
    float wn = sqrtf(fmaxf(wn2, 1e-14f));
    float nv = (2.f / lam) * atanhf(fminf(wn, 1.f - 1e-6f)) * wd / wn;
    float wsum = 0.f;
#pragma unroll
    for (int t = 0; t < 13; ++t) wsum += powf(0.9f, (float)(12 - t));
    float w0 = powf(0.9f, 12.f) / wsum;
    float w12 = 1.f / wsum;
    float velold = U[(size_t)sidx * 512 + 256 + d];
    float vdrop = VOk[(size_t)sidx * 256 + d];
    float velnew = 0.9f * (velold - w0 * vdrop) + w12 * nv;
    U[(size_t)sidx * 512 + 256 + d] = velnew;
  }
}

// ---------------- GEMM4: r = R1(20480 x 512) @ Wr2(512 x 24) + br2, scattered write ----------------
__global__ __launch_bounds__(256) void gemm4_kernel(
    const float* __restrict__ R1, const float* __restrict__ Wr2,
    const float* __restrict__ br2, float* __restrict__ out, int step)
{
  __shared__ float Ws[12288];
  __shared__ float bs[24];
  const int tid = threadIdx.x;
  for (int i = tid; i < 12288; i += 256) Ws[i] = Wr2[i];
  if (tid < 24) bs[tid] = br2[tid];
  __syncthreads();
  const int row = blockIdx.x * 256 + tid;
  float acc[24];
#pragma unroll
  for (int j = 0; j < 24; ++j) acc[j] = bs[j];
  const float* a = &R1[(size_t)row * 512];
  for (int kk = 0; kk < 512; ++kk) {
    float av = a[kk];
#pragma unroll
    for (int j = 0; j < 24; ++j) acc[j] = fmaf(av, Ws[kk * 24 + j], acc[j]);
  }
  const int c = row >> 12, bf = row & 4095, b = bf >> 6, f = bf & 63;
  size_t base = (((size_t)(c * 64 + b) * 96) + (size_t)step * 24) * 64 + f;
#pragma unroll
  for (int j = 0; j < 24; ++j) out[base + (size_t)j * 64] = acc[j];
}

extern "C" void kernel_launch(void* const* d_in, const int* in_sizes, int n_in,
                              void* d_out, int out_size, void* d_ws, size_t ws_size,
                              hipStream_t stream)
{
  const float* trend  = (const float*)d_in[0];
  const float* coarse = (const float*)d_in[1];
  const float* fine   = (const float*)d_in[2];
  const float* resid  = (const float*)d_in[3];
  const float* W_emb  = (const float*)d_in[4];
  const float* b_emb  = (const float*)d_in[5];
  const float* W1  = (const float*)d_in[6];
  const float* b1  = (const float*)d_in[7];
  const float* W2  = (const float*)d_in[8];
  const float* b2  = (const float*)d_in[9];
  const float* Wr1 = (const float*)d_in[10];
  const float* br1 = (const float*)d_in[11];
  const float* Wr2 = (const float*)d_in[12];
  const float* br2 = (const float*)d_in[13];
  float* out = (float*)d_out;

  // workspace layout (floats): U[20480*512] | H[20480*512] | V[20480*256] | ZL[20480*256] | VO[3*20480*256]
  float* U  = (float*)d_ws;
  float* H  = U + (size_t)NSEQ * 512;
  float* V  = H + (size_t)NSEQ * 512;
  float* ZL = V + (size_t)NSEQ * 256;
  float* VO = ZL + (size_t)NSEQ * 256;

  init_kernel<<<NSEQ, 256, 0, stream>>>(trend, coarse, fine, resid, W_emb, b_emb, U, ZL, VO);

  for (int k = 0; k < 4; ++k) {
    // H = tanh(U @ W1 + b1)      (20480x512)@(512x512)
    gemm_f32<1><<<dim3(160, 8), 256, 0, stream>>>(U, 512, W1, 512, b1, H, 512, 512);
    // V = H @ W2 + b2            (20480x512)@(512x256)
    gemm_f32<0><<<dim3(160, 4), 256, 0, stream>>>(H, 512, W2, 256, b2, V, 256, 512);
    // z_next, g -> U[:,0:256], vel update -> U[:,256:512]
    const float* vok = VO + (size_t)(k < 3 ? k : 0) * NSEQ * 256;
    step_kernel<<<NSEQ, 256, 0, stream>>>(V, U, ZL, vok, k);
    // R1 = relu(U[:,0:256] @ Wr1 + br1)   (20480x256)@(256x512), reuse H
    gemm_f32<2><<<dim3(160, 8), 256, 0, stream>>>(U, 512, Wr1, 512, br1, H, 512, 256);
    // out slice = R1 @ Wr2 + br2
    gemm4_kernel<<<NSEQ / 256, 256, 0, stream>>>(H, Wr2, br2, out, k);
  }
}

// Round 2
// 2120.071 us; speedup vs baseline: 1.2815x; 1.2815x over previous
//
#include <hip/hip_runtime.h>
#include <cstddef>

#define NSEQ 20480
#define EPSf 1e-7f
#define MAXN 0.99999f
#define MAXN2d (0.99999 * 0.99999)

// ---------------- wave-wide (64-lane) f64 butterfly sum; all lanes get result ----------------
__device__ __forceinline__ double wave_sum_d(double v) {
#pragma unroll
  for (int off = 32; off > 0; off >>= 1) v += __shfl_xor(v, off);
  return v;
}

// ---------------- init: fold + embed + expmap0 + initial velocity ----------------
// one WAVE per sequence (sidx = c*4096 + b*64 + f); lane holds dims d = lane + 64*j
__global__ __launch_bounds__(256) void init_kernel(
    const float* __restrict__ trend, const float* __restrict__ coarse,
    const float* __restrict__ fine, const float* __restrict__ resid,
    const float* __restrict__ W_emb, const float* __restrict__ b_emb,
    float* __restrict__ U, float* __restrict__ ZL, double* __restrict__ ZN2,
    float* __restrict__ VO)
{
  __shared__ float Ws[24 * 256];   // 24 KB, shared by 4 waves
  __shared__ float segs[4][336];   // per-wave folded series
  const int tid = threadIdx.x;
  const int w = tid >> 6, lane = tid & 63;
  const int sidx = blockIdx.x * 4 + w;
  const int c = sidx >> 12;
  const int bf = sidx & 4095;
  const int b = bf >> 6, f = bf & 63;

  for (int i = tid; i < 24 * 256; i += 256) Ws[i] = W_emb[i];
  for (int l = lane; l < 336; l += 64) {
    size_t idx = ((size_t)b * 336 + l) * 64 + f;
    float v;
    if (c == 0)      v = trend[idx] + coarse[idx] + fine[idx] + resid[idx];
    else if (c == 1) v = trend[idx];
    else if (c == 2) v = coarse[idx];
    else if (c == 3) v = fine[idx];
    else             v = resid[idx];
    segs[w][l] = v;
  }
  __syncthreads();

  float be[4];
#pragma unroll
  for (int j = 0; j < 4; ++j) be[j] = b_emb[lane + 64 * j];

  float z[14][4];      // fully static-indexed -> registers
  double zn2[14];

#pragma unroll
  for (int s = 0; s < 14; ++s) {
    float acc[4] = {be[0], be[1], be[2], be[3]};
#pragma unroll
    for (int g = 0; g < 24; ++g) {
      float sg = segs[w][s * 24 + g];
#pragma unroll
      for (int j = 0; j < 4; ++j)
        acc[j] = fmaf(sg, Ws[g * 256 + lane + 64 * j], acc[j]);
    }
    float e[4];
    double ss = 0.0;
#pragma unroll
    for (int j = 0; j < 4; ++j) { e[j] = tanhf(acc[j]); ss += (double)e[j] * (double)e[j]; }
    double vn2 = wave_sum_d(ss);
    double vn = sqrt(fmax(vn2, 1e-14));
    double tt = (double)tanhf((float)vn);          // ||pre|| == tanh(||e||) exactly
    bool clip = tt > (double)MAXN;
    double scale = (clip ? (double)MAXN : tt) / vn;
#pragma unroll
    for (int j = 0; j < 4; ++j) z[s][j] = (float)(scale * (double)e[j]);
    zn2[s] = clip ? MAXN2d : tt * tt;              // post-project norm^2, analytic
  }

  // decay weights: w[t] = 0.9^(12-t)/wsum, multiplicative walk in f64
  double p12 = 1.0;
#pragma unroll
  for (int i = 0; i < 12; ++i) p12 *= 0.9;
  double wsumd = (1.0 - p12 * 0.9) / 0.1;
  double wt = p12 / wsumd;

  float vel[4] = {0.f, 0.f, 0.f, 0.f};
#pragma unroll
  for (int t = 0; t < 13; ++t) {
    double x2 = zn2[t], y2 = zn2[t + 1];
    double sxy = 0.0;
#pragma unroll
    for (int j = 0; j < 4; ++j) sxy += (double)z[t][j] * (double)z[t + 1][j];
    double xy = wave_sum_d(sxy);
    // w = mobius_add(-x, y):  -(1 - 2xy + y2) x + (1 - x2) y, den = 1 - 2xy + x2 y2
    double den = fmax(1.0 - 2.0 * xy + x2 * y2, 1e-15);
    double a2 = (1.0 - 2.0 * xy + y2) / den;
    double b2 = (1.0 - x2) / den;
    float wd[4];
    double sww = 0.0;
#pragma unroll
    for (int j = 0; j < 4; ++j) {
      wd[j] = (float)(b2 * (double)z[t + 1][j] - a2 * (double)z[t][j]);
      sww += (double)wd[j] * (double)wd[j];
    }
    double wn2 = wave_sum_d(sww);
    double wn = sqrt(fmax(wn2, 1e-14));
    double lam = 2.0 / fmax(1.0 - x2, (double)EPSf);
    float at = atanhf((float)fmin(wn, 1.0 - 1e-6));
    double vls = (2.0 / lam) * (double)at / wn;
#pragma unroll
    for (int j = 0; j < 4; ++j) {
      float vl = (float)(vls * (double)wd[j]);
      vel[j] = (float)((double)vel[j] + wt * (double)vl);
      if (t < 3) VO[(size_t)t * NSEQ * 256 + (size_t)sidx * 256 + lane + 64 * j] = vl;
    }
    wt *= (1.0 / 0.9);
  }

  // U = [logmap0(z13), vel]; ZL = z13; ZN2 = ||z13||^2
  double ynn = sqrt(fmax(zn2[13], 1e-14));
  float at13 = atanhf((float)fmin(ynn, 1.0 - 1e-6));
  double gs = (double)at13 / ynn;
#pragma unroll
  for (int j = 0; j < 4; ++j) {
    int d = lane + 64 * j;
    U[(size_t)sidx * 512 + d] = (float)(gs * (double)z[13][j]);
    U[(size_t)sidx * 512 + 256 + d] = vel[j];
    ZL[(size_t)sidx * 256 + d] = z[13][j];
  }
  if (lane == 0) ZN2[sidx] = zn2[13];
}

// ---------------- f32 tiled GEMM: C(M x N) = epi(A(M x K) @ B(K x N) + bias) ----------------
// block tile 128x64, BK=16, 256 threads, 8x4 micro-tile. EPI: 0 none, 1 tanh, 2 relu
template <int EPI>
__global__ __launch_bounds__(256) void gemm_f32(
    const float* __restrict__ A, int lda,
    const float* __restrict__ B, int ldb,
    const float* __restrict__ bias,
    float* __restrict__ C, int ldc, int K)
{
  __shared__ float As[16][128];
  __shared__ float Bs[16][64];
  const int tid = threadIdx.x;
  const int row0 = blockIdx.x * 128;
  const int col0 = blockIdx.y * 64;
  const int am = tid >> 1;
  const int ak = (tid & 1) * 8;
  const int bk = tid >> 4;
  const int bn = (tid & 15) * 4;
  const int tx = tid & 15, ty = tid >> 4;
  float acc[8][4];
#pragma unroll
  for (int i = 0; i < 8; ++i)
#pragma unroll
    for (int j = 0; j < 4; ++j) acc[i][j] = 0.f;

  for (int k0 = 0; k0 < K; k0 += 16) {
    float4 a0 = *(const float4*)&A[(size_t)(row0 + am) * lda + k0 + ak];
    float4 a1 = *(const float4*)&A[(size_t)(row0 + am) * lda + k0 + ak + 4];
    float4 bv = *(const float4*)&B[(size_t)(k0 + bk) * ldb + col0 + bn];
    As[ak + 0][am] = a0.x; As[ak + 1][am] = a0.y; As[ak + 2][am] = a0.z; As[ak + 3][am] = a0.w;
    As[ak + 4][am] = a1.x; As[ak + 5][am] = a1.y; As[ak + 6][am] = a1.z; As[ak + 7][am] = a1.w;
    *(float4*)&Bs[bk][bn] = bv;
    __syncthreads();
#pragma unroll
    for (int kk = 0; kk < 16; ++kk) {
      float4 av0 = *(const float4*)&As[kk][ty * 8];
      float4 av1 = *(const float4*)&As[kk][ty * 8 + 4];
      float4 bvv = *(const float4*)&Bs[kk][tx * 4];
      float ar[8] = {av0.x, av0.y, av0.z, av0.w, av1.x, av1.y, av1.z, av1.w};
      float br[4] = {bvv.x, bvv.y, bvv.z, bvv.w};
#pragma unroll
      for (int i = 0; i < 8; ++i)
#pragma unroll
        for (int j = 0; j < 4; ++j) acc[i][j] = fmaf(ar[i], br[j], acc[i][j]);
    }
    __syncthreads();
  }
#pragma unroll
  for (int i = 0; i < 8; ++i) {
    const int row = row0 + ty * 8 + i;
    float t0[4];
#pragma unroll
    for (int j = 0; j < 4; ++j) {
      float vv = acc[i][j] + bias[col0 + tx * 4 + j];
      if (EPI == 1) vv = tanhf(vv);
      else if (EPI == 2) vv = fmaxf(vv, 0.f);
      t0[j] = vv;
    }
    float4 o = {t0[0], t0[1], t0[2], t0[3]};
    *(float4*)&C[(size_t)row * ldc + col0 + tx * 4] = o;
  }
}

// ---------------- per-sequence step (one WAVE per sequence) ----------------
__global__ __launch_bounds__(256) void step_kernel(
    const float* __restrict__ V, float* __restrict__ U,
    float* __restrict__ ZL, double* __restrict__ ZN2,
    const float* __restrict__ VOk, int k)
{
  const int tid = threadIdx.x;
  const int w = tid >> 6, lane = tid & 63;
  const int sidx = blockIdx.x * 4 + w;

  float x[4], v[4];
#pragma unroll
  for (int j = 0; j < 4; ++j) {
    x[j] = ZL[(size_t)sidx * 256 + lane + 64 * j];
    v[j] = V[(size_t)sidx * 256 + lane + 64 * j];
  }
  double x2 = ZN2[sidx];

  double sxv = 0.0, svv = 0.0;
#pragma unroll
  for (int j = 0; j < 4; ++j) {
    sxv += (double)x[j] * (double)v[j];
    svv += (double)v[j] * (double)v[j];
  }
  double xv = wave_sum_d(sxv);
  double vn2 = wave_sum_d(svv);
  double vn = sqrt(fmax(vn2, 1e-14));
  double lam = 2.0 / fmax(1.0 - x2, (double)EPSf);
  double th = (double)tanhf((float)(lam * vn * 0.5));
  double sec_s = th / vn;                 // sec = sec_s * v
  double y2 = th * th;                    // ||sec||^2 analytic
  double xy = sec_s * xv;                 // <x, sec> analytic
  double den = fmax(1.0 + 2.0 * xy + x2 * y2, 1e-15);
  double alpha = (1.0 + 2.0 * xy + y2) / den;
  double beta  = (1.0 - x2) * sec_s / den;   // zn_pre = alpha*x + beta*v

  float zn[4];
  double snn = 0.0;
#pragma unroll
  for (int j = 0; j < 4; ++j) {
    zn[j] = (float)(alpha * (double)x[j] + beta * (double)v[j]);
    snn += (double)zn[j] * (double)zn[j];
  }
  double n2 = wave_sum_d(snn);
  double n = sqrt(fmax(n2, 1e-14));
  bool clip = n > (double)MAXN;
  double scl = clip ? (double)MAXN / n : 1.0;
  double z2 = clip ? MAXN2d : n2;
#pragma unroll
  for (int j = 0; j < 4; ++j) {
    zn[j] = (float)((double)zn[j] * scl);
    ZL[(size_t)sidx * 256 + lane + 64 * j] = zn[j];
  }
  if (lane == 0) ZN2[sidx] = z2;

  // logmap0(z_next) -> U[:, 0:256]
  double ynn = sqrt(fmax(z2, 1e-14));
  float at = atanhf((float)fmin(ynn, 1.0 - 1e-6));
  double gs = (double)at / ynn;
#pragma unroll
  for (int j = 0; j < 4; ++j)
    U[(size_t)sidx * 512 + lane + 64 * j] = (float)(gs * (double)zn[j]);

  if (k < 3) {
    // <x, z_next> analytic: scl*(alpha*x2 + beta*xv)
    double xy2 = scl * (alpha * x2 + beta * xv);
    double y2n = z2;
    double den2 = fmax(1.0 - 2.0 * xy2 + x2 * y2n, 1e-15);
    double a2 = (1.0 - 2.0 * xy2 + y2n) / den2;
    double b2 = (1.0 - x2) / den2;
    float wv[4];
    double sww = 0.0;
#pragma unroll
    for (int j = 0; j < 4; ++j) {
      wv[j] = (float)(b2 * (double)zn[j] - a2 * (double)x[j]);
      sww += (double)wv[j] * (double)wv[j];
    }
    double wn2 = wave_sum_d(sww);
    double wn = sqrt(fmax(wn2, 1e-14));
    float atw = atanhf((float)fmin(wn, 1.0 - 1e-6));
    double vls = (2.0 / lam) * (double)atw / wn;

    double p12 = 1.0;
#pragma unroll
    for (int i = 0; i < 12; ++i) p12 *= 0.9;
    double wsumd = (1.0 - p12 * 0.9) / 0.1;
    double w0 = p12 / wsumd;
    double w12 = 1.0 / wsumd;
#pragma unroll
    for (int j = 0; j < 4; ++j) {
      float velold = U[(size_t)sidx * 512 + 256 + lane + 64 * j];
      float vdrop = VOk[(size_t)sidx * 256 + lane + 64 * j];
      float velnew = (float)(0.9 * ((double)velold - w0 * (double)vdrop) + w12 * (vls * (double)wv[j]));
      U[(size_t)sidx * 512 + 256 + lane + 64 * j] = velnew;
    }
  }
}

// ---------------- GEMM4: r = R1(20480 x 512) @ Wr2(512 x 24) + br2, scattered write ----------------
__global__ __launch_bounds__(256) void gemm4_kernel(
    const float* __restrict__ R1, const float* __restrict__ Wr2,
    const float* __restrict__ br2, float* __restrict__ out, int step)
{
  __shared__ float Ws[12288];
  __shared__ float bs[24];
  const int tid = threadIdx.x;
  for (int i = tid; i < 12288; i += 256) Ws[i] = Wr2[i];
  if (tid < 24) bs[tid] = br2[tid];
  __syncthreads();
  const int row = blockIdx.x * 256 + tid;
  float acc[24];
#pragma unroll
  for (int j = 0; j < 24; ++j) acc[j] = bs[j];
  const float* a = &R1[(size_t)row * 512];
  for (int kk = 0; kk < 512; ++kk) {
    float av = a[kk];
#pragma unroll
    for (int j = 0; j < 24; ++j) acc[j] = fmaf(av, Ws[kk * 24 + j], acc[j]);
  }
  const int c = row >> 12, bf = row & 4095, b = bf >> 6, f = bf & 63;
  size_t base = (((size_t)(c * 64 + b) * 96) + (size_t)step * 24) * 64 + f;
#pragma unroll
  for (int j = 0; j < 24; ++j) out[base + (size_t)j * 64] = acc[j];
}

extern "C" void kernel_launch(void* const* d_in, const int* in_sizes, int n_in,
                              void* d_out, int out_size, void* d_ws, size_t ws_size,
                              hipStream_t stream)
{
  const float* trend  = (const float*)d_in[0];
  const float* coarse = (const float*)d_in[1];
  const float* fine   = (const float*)d_in[2];
  const float* resid  = (const float*)d_in[3];
  const float* W_emb  = (const float*)d_in[4];
  const float* b_emb  = (const float*)d_in[5];
  const float* W1  = (const float*)d_in[6];
  const float* b1  = (const float*)d_in[7];
  const float* W2  = (const float*)d_in[8];
  const float* b2  = (const float*)d_in[9];
  const float* Wr1 = (const float*)d_in[10];
  const float* br1 = (const float*)d_in[11];
  const float* Wr2 = (const float*)d_in[12];
  const float* br2 = (const float*)d_in[13];
  float* out = (float*)d_out;

  // ws (floats): U[20480*512] | H[20480*512] | V[20480*256] | ZL[20480*256] | ZN2(double)[20480] | VO[3*20480*256]
  float* U  = (float*)d_ws;
  float* H  = U + (size_t)NSEQ * 512;
  float* V  = H + (size_t)NSEQ * 512;
  float* ZL = V + (size_t)NSEQ * 256;
  double* ZN2 = (double*)(ZL + (size_t)NSEQ * 256);
  float* VO = (float*)(ZN2 + NSEQ);

  init_kernel<<<NSEQ / 4, 256, 0, stream>>>(trend, coarse, fine, resid, W_emb, b_emb, U, ZL, ZN2, VO);

  for (int k = 0; k < 4; ++k) {
    // H = tanh(U @ W1 + b1)      (20480x512)@(512x512)
    gemm_f32<1><<<dim3(160, 8), 256, 0, stream>>>(U, 512, W1, 512, b1, H, 512, 512);
    // V = H @ W2 + b2            (20480x512)@(512x256)
    gemm_f32<0><<<dim3(160, 4), 256, 0, stream>>>(H, 512, W2, 256, b2, V, 256, 512);
    // z_next, logmap0 -> U[:,0:256], vel update -> U[:,256:512]
    const float* vok = VO + (size_t)(k < 3 ? k : 0) * NSEQ * 256;
    step_kernel<<<NSEQ / 4, 256, 0, stream>>>(V, U, ZL, ZN2, vok, k);
    // R1 = relu(U[:,0:256] @ Wr1 + br1)   (20480x256)@(256x512), reuse H
    gemm_f32<2><<<dim3(160, 8), 256, 0, stream>>>(U, 512, Wr1, 512, br1, H, 512, 256);
    // out slice = R1 @ Wr2 + br2
    gemm4_kernel<<<NSEQ / 256, 256, 0, stream>>>(H, Wr2, br2, out, k);
  }
}

// Round 3
// 924.254 us; speedup vs baseline: 2.9395x; 2.2938x over previous
//
#include <hip/hip_runtime.h>
#include <cstddef>

#define NSEQ 20480
#define EPSf 1e-7f
#define MAXN 0.99999f
#define MAXN2 (0.99999f * 0.99999f)

typedef __attribute__((ext_vector_type(8))) short bf16x8;
typedef __attribute__((ext_vector_type(4))) float f32x4;

__device__ __forceinline__ unsigned short f2bf(float x) {
  unsigned u = __float_as_uint(x);
  u += 0x7FFF + ((u >> 16) & 1);
  return (unsigned short)(u >> 16);
}
__device__ __forceinline__ float bf2f(unsigned short h) {
  return __uint_as_float(((unsigned)h) << 16);
}
__device__ __forceinline__ double wave_sum_d(double v) {
#pragma unroll
  for (int off = 32; off > 0; off >>= 1) v += __shfl_xor(v, off);
  return v;
}

// ---------------- fold transpose: X[b][l][f] (4 arrays) -> XT[ch][b*64+f][l], ch0 = sum ----------------
__global__ __launch_bounds__(256) void fold_transpose(
    const float* __restrict__ t, const float* __restrict__ c,
    const float* __restrict__ f, const float* __restrict__ r,
    float* __restrict__ XT)
{
  __shared__ float tile[4][56][65];
  const int b = blockIdx.x, l0 = blockIdx.y * 56;
  const int tid = threadIdx.x;
  const int fi = tid & 63, lr0 = tid >> 6;
#pragma unroll
  for (int i = 0; i < 14; ++i) {
    int lr = lr0 + i * 4;
    size_t idx = ((size_t)b * 336 + l0 + lr) * 64 + fi;
    tile[0][lr][fi] = t[idx];
    tile[1][lr][fi] = c[idx];
    tile[2][lr][fi] = f[idx];
    tile[3][lr][fi] = r[idx];
  }
  __syncthreads();
#pragma unroll
  for (int ch = 0; ch < 5; ++ch) {
    for (int i = 0; i < 14; ++i) {
      int idx2 = i * 256 + tid;
      int ff = idx2 / 56, ll = idx2 % 56;
      float v;
      if (ch == 0) v = tile[0][ll][ff] + tile[1][ll][ff] + tile[2][ll][ff] + tile[3][ll][ff];
      else v = tile[ch - 1][ll][ff];
      XT[((size_t)ch * 4096 + (b << 6) + ff) * 336 + l0 + ll] = v;
    }
  }
}

// ---------------- weight split+tile: W[k][n] f32 -> Wh/Wl bf16 at [(k>>3)*N + n]*8 + (k&7) ----------------
__global__ __launch_bounds__(256) void conv_weight(
    const float* __restrict__ W, unsigned short* __restrict__ Wh, unsigned short* __restrict__ Wl,
    int K, int N, int Nsrc)
{
  int idx = blockIdx.x * 256 + threadIdx.x;
  if (idx >= K * N) return;
  int k = idx / N, n = idx % N;
  float x = (n < Nsrc) ? W[(size_t)k * Nsrc + n] : 0.f;
  unsigned short h = f2bf(x);
  size_t o = ((size_t)(k >> 3) * N + n) * 8 + (k & 7);
  Wh[o] = h;
  Wl[o] = f2bf(x - bf2f(h));
}

// ---------------- init: embed + expmap0 + initial velocity, one WAVE per sequence ----------------
__global__ __launch_bounds__(256) void init_kernel(
    const float* __restrict__ XT, const float* __restrict__ W_emb, const float* __restrict__ b_emb,
    unsigned short* __restrict__ Uh, unsigned short* __restrict__ Ul,
    float* __restrict__ ZL, float* __restrict__ ZN2, unsigned short* __restrict__ VO)
{
  __shared__ float segs[4][336];
  const int tid = threadIdx.x, w = tid >> 6, lane = tid & 63;
  const int sidx = blockIdx.x * 4 + w;

  float Wreg[24][4];
#pragma unroll
  for (int g = 0; g < 24; ++g)
#pragma unroll
    for (int j = 0; j < 4; ++j) Wreg[g][j] = W_emb[g * 256 + lane + 64 * j];
  float be[4];
#pragma unroll
  for (int j = 0; j < 4; ++j) be[j] = b_emb[lane + 64 * j];

  const float* src = XT + (size_t)sidx * 336;
  for (int l = lane; l < 336; l += 64) segs[w][l] = src[l];
  // segs[w] is wave-private: no block barrier needed (same-wave LDS ordering)

  // decay weights
  float p12 = 1.f;
#pragma unroll
  for (int i = 0; i < 12; ++i) p12 *= 0.9f;
  float wsum = (1.f - p12 * 0.9f) / 0.1f;
  float wt = p12 / wsum;

  float zp[4], zc[4], x2p = 0.f, x2c = 0.f;
  float vel[4] = {0.f, 0.f, 0.f, 0.f};

#pragma unroll
  for (int s = 0; s < 14; ++s) {
    float acc[4] = {be[0], be[1], be[2], be[3]};
#pragma unroll
    for (int g = 0; g < 24; ++g) {
      float sg = segs[w][s * 24 + g];
#pragma unroll
      for (int j = 0; j < 4; ++j) acc[j] = fmaf(sg, Wreg[g][j], acc[j]);
    }
    float e[4];
    double ss = 0.0;
#pragma unroll
    for (int j = 0; j < 4; ++j) { e[j] = tanhf(acc[j]); ss += (double)e[j] * (double)e[j]; }
    float vn2 = (float)wave_sum_d(ss);
    float vn = sqrtf(fmaxf(vn2, 1e-14f));
    float tt = tanhf(vn);                    // ||expmap0 pre|| == tanh(||e||) exactly
    bool clip = tt > MAXN;
    float scale = (clip ? MAXN : tt) / vn;
#pragma unroll
    for (int j = 0; j < 4; ++j) zc[j] = scale * e[j];
    x2c = clip ? MAXN2 : tt * tt;

    if (s > 0) {
      const int tstep = s - 1;
      double sxy = 0.0;
#pragma unroll
      for (int j = 0; j < 4; ++j) sxy += (double)zp[j] * (double)zc[j];
      float xy = (float)wave_sum_d(sxy);
      float den = fmaxf(1.f - 2.f * xy + x2p * x2c, 1e-15f);
      float a2 = (1.f - 2.f * xy + x2c) / den;
      float b2 = (1.f - x2p) / den;
      float wd[4];
      double sww = 0.0;
#pragma unroll
      for (int j = 0; j < 4; ++j) {
        wd[j] = b2 * zc[j] - a2 * zp[j];
        sww += (double)wd[j] * (double)wd[j];
      }
      float wn2 = (float)wave_sum_d(sww);
      float wn = sqrtf(fmaxf(wn2, 1e-14f));
      float twoOverLam = fmaxf(1.f - x2p, EPSf);    // = 2/lam
      float vls = twoOverLam * atanhf(fminf(wn, 1.f - 1e-6f)) / wn;
#pragma unroll
      for (int j = 0; j < 4; ++j) {
        float vl = vls * wd[j];
        vel[j] = fmaf(wt, vl, vel[j]);
        if (tstep < 3)
          VO[((size_t)tstep * NSEQ + sidx) * 256 + lane + 64 * j] = f2bf(vl);
      }
      wt *= (1.f / 0.9f);
    }
#pragma unroll
    for (int j = 0; j < 4; ++j) zp[j] = zc[j];
    x2p = x2c;
  }

  // U = [logmap0(z13), vel] split bf16; ZL = z13; ZN2 = ||z13||^2
  float ynn = sqrtf(fmaxf(x2c, 1e-14f));
  float gs = atanhf(fminf(ynn, 1.f - 1e-6f)) / ynn;
#pragma unroll
  for (int j = 0; j < 4; ++j) {
    int d = lane + 64 * j;
    float g = gs * zc[j];
    unsigned short gh = f2bf(g);
    Uh[(size_t)sidx * 512 + d] = gh;
    Ul[(size_t)sidx * 512 + d] = f2bf(g - bf2f(gh));
    unsigned short vh = f2bf(vel[j]);
    Uh[(size_t)sidx * 512 + 256 + d] = vh;
    Ul[(size_t)sidx * 512 + 256 + d] = f2bf(vel[j] - bf2f(vh));
    ZL[(size_t)sidx * 256 + d] = zc[j];
  }
  if (lane == 0) ZN2[sidx] = x2c;
}

// ---------------- split-bf16 MFMA GEMM: C = epi(A @ B + bias), 128x128 tile, BK=32 ----------------
// A: hi/lo bf16 planes, row-major M x lda. B: hi/lo tiled [K/8][N][8].
// EPI: 0 -> f32 out Cf; 1 -> tanh, split out Ch/Cl; 2 -> relu, split out Ch/Cl
template <int EPI>
__global__ __launch_bounds__(256) void gemm_split(
    const unsigned short* __restrict__ Ah, const unsigned short* __restrict__ Al, int lda, int K,
    const unsigned short* __restrict__ Bh, const unsigned short* __restrict__ Bl, int N,
    const float* __restrict__ bias,
    float* __restrict__ Cf, unsigned short* __restrict__ Ch, unsigned short* __restrict__ Cl, int ldc)
{
  __shared__ unsigned short As[2][4][128][8];
  __shared__ unsigned short Bs[2][4][128][8];
  const int tid = threadIdx.x;
  const int lane = tid & 63, wid = tid >> 6;
  const int wr = wid >> 1, wc = wid & 1;
  const int l15 = lane & 15, l4 = lane >> 4;
  const int row0 = blockIdx.x * 128, col0 = blockIdx.y * 128;

  f32x4 acc[4][4];
#pragma unroll
  for (int i = 0; i < 4; ++i)
#pragma unroll
    for (int j = 0; j < 4; ++j) acc[i][j] = (f32x4){0.f, 0.f, 0.f, 0.f};

  const int sm = tid >> 2, skg = tid & 3;         // A chunks: (m, kg) and (m+64, kg)
  const int bn = tid & 127, bkg0 = tid >> 7;      // B chunks: (kg0, n) and (kg0+2, n)

  for (int k0 = 0; k0 < K; k0 += 32) {
    size_t abase = (size_t)(row0 + sm) * lda + k0 + skg * 8;
    *(uint4*)&As[0][skg][sm][0] = *(const uint4*)&Ah[abase];
    *(uint4*)&As[1][skg][sm][0] = *(const uint4*)&Al[abase];
    size_t abase2 = abase + (size_t)64 * lda;
    *(uint4*)&As[0][skg][sm + 64][0] = *(const uint4*)&Ah[abase2];
    *(uint4*)&As[1][skg][sm + 64][0] = *(const uint4*)&Al[abase2];
    size_t bbase = ((size_t)((k0 >> 3) + bkg0) * N + col0 + bn) * 8;
    *(uint4*)&Bs[0][bkg0][bn][0] = *(const uint4*)&Bh[bbase];
    *(uint4*)&Bs[1][bkg0][bn][0] = *(const uint4*)&Bl[bbase];
    size_t bbase2 = bbase + (size_t)2 * N * 8;
    *(uint4*)&Bs[0][bkg0 + 2][bn][0] = *(const uint4*)&Bh[bbase2];
    *(uint4*)&Bs[1][bkg0 + 2][bn][0] = *(const uint4*)&Bl[bbase2];
    __syncthreads();

    bf16x8 fah[4], fal[4], fbh[4], fbl[4];
#pragma unroll
    for (int mi = 0; mi < 4; ++mi) {
      fah[mi] = *(const bf16x8*)&As[0][l4][wr * 64 + mi * 16 + l15][0];
      fal[mi] = *(const bf16x8*)&As[1][l4][wr * 64 + mi * 16 + l15][0];
    }
#pragma unroll
    for (int ni = 0; ni < 4; ++ni) {
      fbh[ni] = *(const bf16x8*)&Bs[0][l4][wc * 64 + ni * 16 + l15][0];
      fbl[ni] = *(const bf16x8*)&Bs[1][l4][wc * 64 + ni * 16 + l15][0];
    }
#pragma unroll
    for (int mi = 0; mi < 4; ++mi)
#pragma unroll
      for (int ni = 0; ni < 4; ++ni) {
        acc[mi][ni] = __builtin_amdgcn_mfma_f32_16x16x32_bf16(fah[mi], fbh[ni], acc[mi][ni], 0, 0, 0);
        acc[mi][ni] = __builtin_amdgcn_mfma_f32_16x16x32_bf16(fah[mi], fbl[ni], acc[mi][ni], 0, 0, 0);
        acc[mi][ni] = __builtin_amdgcn_mfma_f32_16x16x32_bf16(fal[mi], fbh[ni], acc[mi][ni], 0, 0, 0);
      }
    __syncthreads();
  }

#pragma unroll
  for (int mi = 0; mi < 4; ++mi)
#pragma unroll
    for (int ni = 0; ni < 4; ++ni) {
      int cc = col0 + wc * 64 + ni * 16 + l15;
      float bv = bias[cc];
      int rbase = row0 + wr * 64 + mi * 16 + l4 * 4;
#pragma unroll
      for (int r = 0; r < 4; ++r) {
        float v = acc[mi][ni][r] + bv;
        if (EPI == 1) v = tanhf(v);
        else if (EPI == 2) v = fmaxf(v, 0.f);
        if (EPI == 0) {
          Cf[(size_t)(rbase + r) * ldc + cc] = v;
        } else {
          unsigned short h = f2bf(v);
          Ch[(size_t)(rbase + r) * ldc + cc] = h;
          Cl[(size_t)(rbase + r) * ldc + cc] = f2bf(v - bf2f(h));
        }
      }
    }
}

// ---------------- per-sequence step (one WAVE per sequence), f32 scalars ----------------
__global__ __launch_bounds__(256) void step_kernel(
    const float* __restrict__ V, unsigned short* __restrict__ Uh, unsigned short* __restrict__ Ul,
    float* __restrict__ ZL, float* __restrict__ ZN2, const unsigned short* __restrict__ VOk, int k)
{
  const int tid = threadIdx.x, w = tid >> 6, lane = tid & 63;
  const int sidx = blockIdx.x * 4 + w;

  float x[4], v[4];
#pragma unroll
  for (int j = 0; j < 4; ++j) {
    x[j] = ZL[(size_t)sidx * 256 + lane + 64 * j];
    v[j] = V[(size_t)sidx * 256 + lane + 64 * j];
  }
  float x2 = ZN2[sidx];

  double sxv = 0.0, svv = 0.0;
#pragma unroll
  for (int j = 0; j < 4; ++j) {
    sxv += (double)x[j] * (double)v[j];
    svv += (double)v[j] * (double)v[j];
  }
  float xv = (float)wave_sum_d(sxv);
  float vn2 = (float)wave_sum_d(svv);
  float vn = sqrtf(fmaxf(vn2, 1e-14f));
  float twoOverLam = fmaxf(1.f - x2, EPSf);           // = 2/lam
  float th = tanhf(vn / twoOverLam);                  // tanh(lam*vn/2)
  float sec_s = th / vn;                              // sec = sec_s * v
  float y2 = th * th;
  float xy = sec_s * xv;
  float den = fmaxf(1.f + 2.f * xy + x2 * y2, 1e-15f);
  float alpha = (1.f + 2.f * xy + y2) / den;
  float beta = (1.f - x2) * sec_s / den;

  float zn[4];
  double snn = 0.0;
#pragma unroll
  for (int j = 0; j < 4; ++j) {
    zn[j] = alpha * x[j] + beta * v[j];
    snn += (double)zn[j] * (double)zn[j];
  }
  float n2 = (float)wave_sum_d(snn);
  float n = sqrtf(fmaxf(n2, 1e-14f));
  bool clip = n > MAXN;
  float scl = clip ? MAXN / n : 1.f;
  float z2 = clip ? MAXN2 : n2;
#pragma unroll
  for (int j = 0; j < 4; ++j) {
    zn[j] *= scl;
    ZL[(size_t)sidx * 256 + lane + 64 * j] = zn[j];
  }
  if (lane == 0) ZN2[sidx] = z2;

  float ynn = sqrtf(fmaxf(z2, 1e-14f));
  float gs = atanhf(fminf(ynn, 1.f - 1e-6f)) / ynn;
#pragma unroll
  for (int j = 0; j < 4; ++j) {
    float g = gs * zn[j];
    unsigned short gh = f2bf(g);
    Uh[(size_t)sidx * 512 + lane + 64 * j] = gh;
    Ul[(size_t)sidx * 512 + lane + 64 * j] = f2bf(g - bf2f(gh));
  }

  if (k < 3) {
    float xy2 = scl * (alpha * x2 + beta * xv);       // <x, z_next> analytic
    float den2 = fmaxf(1.f - 2.f * xy2 + x2 * z2, 1e-15f);
    float a2 = (1.f - 2.f * xy2 + z2) / den2;
    float b2 = (1.f - x2) / den2;
    float wv[4];
    double sww = 0.0;
#pragma unroll
    for (int j = 0; j < 4; ++j) {
      wv[j] = b2 * zn[j] - a2 * x[j];
      sww += (double)wv[j] * (double)wv[j];
    }
    float wn2 = (float)wave_sum_d(sww);
    float wn = sqrtf(fmaxf(wn2, 1e-14f));
    float vls = twoOverLam * atanhf(fminf(wn, 1.f - 1e-6f)) / wn;

    float p12 = 1.f;
#pragma unroll
    for (int i = 0; i < 12; ++i) p12 *= 0.9f;
    float wsum = (1.f - p12 * 0.9f) / 0.1f;
    float w0 = p12 / wsum;
    float w12 = 1.f / wsum;
#pragma unroll
    for (int j = 0; j < 4; ++j) {
      int d = 256 + lane + 64 * j;
      float velold = bf2f(Uh[(size_t)sidx * 512 + d]) + bf2f(Ul[(size_t)sidx * 512 + d]);
      float vdrop = bf2f(VOk[(size_t)sidx * 256 + lane + 64 * j]);
      float velnew = 0.9f * (velold - w0 * vdrop) + w12 * (vls * wv[j]);
      unsigned short vh = f2bf(velnew);
      Uh[(size_t)sidx * 512 + d] = vh;
      Ul[(size_t)sidx * 512 + d] = f2bf(velnew - bf2f(vh));
    }
  }
}

// ---------------- GEMM4 (MFMA): r = R1(20480x512) @ Wr2(512x24->32) + br2, scattered write ----------------
__global__ __launch_bounds__(256) void gemm4_mfma(
    const unsigned short* __restrict__ Ah, const unsigned short* __restrict__ Al,
    const unsigned short* __restrict__ Bh, const unsigned short* __restrict__ Bl,
    const float* __restrict__ br2, float* __restrict__ out, int step)
{
  __shared__ unsigned short As[2][4][128][8];
  __shared__ unsigned short Bs[2][4][32][8];
  const int tid = threadIdx.x, lane = tid & 63, wid = tid >> 6;
  const int l15 = lane & 15, l4 = lane >> 4;
  const int row0 = blockIdx.x * 128;

  f32x4 acc[2][2];
#pragma unroll
  for (int i = 0; i < 2; ++i)
#pragma unroll
    for (int j = 0; j < 2; ++j) acc[i][j] = (f32x4){0.f, 0.f, 0.f, 0.f};

  const int sm = tid >> 2, skg = tid & 3;
  const int bplane = tid >> 7, bc = tid & 127, bkg = bc >> 5, bnn = bc & 31;
  const unsigned short* Bp = bplane ? Bl : Bh;

  for (int k0 = 0; k0 < 512; k0 += 32) {
    size_t abase = (size_t)(row0 + sm) * 512 + k0 + skg * 8;
    *(uint4*)&As[0][skg][sm][0] = *(const uint4*)&Ah[abase];
    *(uint4*)&As[1][skg][sm][0] = *(const uint4*)&Al[abase];
    size_t abase2 = abase + (size_t)64 * 512;
    *(uint4*)&As[0][skg][sm + 64][0] = *(const uint4*)&Ah[abase2];
    *(uint4*)&As[1][skg][sm + 64][0] = *(const uint4*)&Al[abase2];
    size_t bbase = ((size_t)((k0 >> 3) + bkg) * 32 + bnn) * 8;
    *(uint4*)&Bs[bplane][bkg][bnn][0] = *(const uint4*)&Bp[bbase];
    __syncthreads();

    bf16x8 fah[2], fal[2], fbh[2], fbl[2];
#pragma unroll
    for (int mi = 0; mi < 2; ++mi) {
      fah[mi] = *(const bf16x8*)&As[0][l4][wid * 32 + mi * 16 + l15][0];
      fal[mi] = *(const bf16x8*)&As[1][l4][wid * 32 + mi * 16 + l15][0];
    }
#pragma unroll
    for (int ni = 0; ni < 2; ++ni) {
      fbh[ni] = *(const bf16x8*)&Bs[0][l4][ni * 16 + l15][0];
      fbl[ni] = *(const bf16x8*)&Bs[1][l4][ni * 16 + l15][0];
    }
#pragma unroll
    for (int mi = 0; mi < 2; ++mi)
#pragma unroll
      for (int ni = 0; ni < 2; ++ni) {
        acc[mi][ni] = __builtin_amdgcn_mfma_f32_16x16x32_bf16(fah[mi], fbh[ni], acc[mi][ni], 0, 0, 0);
        acc[mi][ni] = __builtin_amdgcn_mfma_f32_16x16x32_bf16(fah[mi], fbl[ni], acc[mi][ni], 0, 0, 0);
        acc[mi][ni] = __builtin_amdgcn_mfma_f32_16x16x32_bf16(fal[mi], fbh[ni], acc[mi][ni], 0, 0, 0);
      }
    __syncthreads();
  }

#pragma unroll
  for (int mi = 0; mi < 2; ++mi)
#pragma unroll
    for (int ni = 0; ni < 2; ++ni) {
      int j = ni * 16 + l15;
      if (j < 24) {
        float bv = br2[j];
#pragma unroll
        for (int r = 0; r < 4; ++r) {
          int row = row0 + wid * 32 + mi * 16 + l4 * 4 + r;
          int c = row >> 12, bf = row & 4095, b = bf >> 6, f = bf & 63;
          size_t base = (((size_t)(c * 64 + b) * 96) + (size_t)step * 24 + j) * 64 + f;
          out[base] = acc[mi][ni][r] + bv;
        }
      }
    }
}

extern "C" void kernel_launch(void* const* d_in, const int* in_sizes, int n_in,
                              void* d_out, int out_size, void* d_ws, size_t ws_size,
                              hipStream_t stream)
{
  const float* trend  = (const float*)d_in[0];
  const float* coarse = (const float*)d_in[1];
  const float* fine   = (const float*)d_in[2];
  const float* resid  = (const float*)d_in[3];
  const float* W_emb  = (const float*)d_in[4];
  const float* b_emb  = (const float*)d_in[5];
  const float* W1  = (const float*)d_in[6];
  const float* b1  = (const float*)d_in[7];
  const float* W2  = (const float*)d_in[8];
  const float* b2  = (const float*)d_in[9];
  const float* Wr1 = (const float*)d_in[10];
  const float* br1 = (const float*)d_in[11];
  const float* Wr2 = (const float*)d_in[12];
  const float* br2 = (const float*)d_in[13];
  float* out = (float*)d_out;

  // workspace layout (≈187.0 MB total, 256B-aligned chunks)
  char* p = (char*)d_ws;
  size_t off = 0;
  auto alloc = [&](size_t bytes) -> void* {
    void* r = p + off;
    off = (off + bytes + 255) & ~(size_t)255;
    return r;
  };
  unsigned short* Uh = (unsigned short*)alloc((size_t)NSEQ * 512 * 2);
  unsigned short* Ul = (unsigned short*)alloc((size_t)NSEQ * 512 * 2);
  unsigned short* Hh = (unsigned short*)alloc((size_t)NSEQ * 512 * 2);
  unsigned short* Hl = (unsigned short*)alloc((size_t)NSEQ * 512 * 2);
  float* V   = (float*)alloc((size_t)NSEQ * 256 * 4);
  float* ZL  = (float*)alloc((size_t)NSEQ * 256 * 4);
  float* ZN2 = (float*)alloc((size_t)NSEQ * 4);
  unsigned short* VO = (unsigned short*)alloc((size_t)3 * NSEQ * 256 * 2);
  float* XT  = (float*)alloc((size_t)5 * 4096 * 336 * 4);
  unsigned short* W1h = (unsigned short*)alloc((size_t)512 * 512 * 2);
  unsigned short* W1l = (unsigned short*)alloc((size_t)512 * 512 * 2);
  unsigned short* W2h = (unsigned short*)alloc((size_t)512 * 256 * 2);
  unsigned short* W2l = (unsigned short*)alloc((size_t)512 * 256 * 2);
  unsigned short* Wr1h = (unsigned short*)alloc((size_t)256 * 512 * 2);
  unsigned short* Wr1l = (unsigned short*)alloc((size_t)256 * 512 * 2);
  unsigned short* Wr2h = (unsigned short*)alloc((size_t)512 * 32 * 2);
  unsigned short* Wr2l = (unsigned short*)alloc((size_t)512 * 32 * 2);

  fold_transpose<<<dim3(64, 6), 256, 0, stream>>>(trend, coarse, fine, resid, XT);
  conv_weight<<<(512 * 512 + 255) / 256, 256, 0, stream>>>(W1, W1h, W1l, 512, 512, 512);
  conv_weight<<<(512 * 256 + 255) / 256, 256, 0, stream>>>(W2, W2h, W2l, 512, 256, 256);
  conv_weight<<<(256 * 512 + 255) / 256, 256, 0, stream>>>(Wr1, Wr1h, Wr1l, 256, 512, 512);
  conv_weight<<<(512 * 32 + 255) / 256, 256, 0, stream>>>(Wr2, Wr2h, Wr2l, 512, 32, 24);
  init_kernel<<<NSEQ / 4, 256, 0, stream>>>(XT, W_emb, b_emb, Uh, Ul, ZL, ZN2, VO);

  for (int k = 0; k < 4; ++k) {
    // H = tanh(U @ W1 + b1)   (20480x512)@(512x512), split out
    gemm_split<1><<<dim3(160, 4), 256, 0, stream>>>(Uh, Ul, 512, 512, W1h, W1l, 512, b1,
                                                    nullptr, Hh, Hl, 512);
    // V = H @ W2 + b2         (20480x512)@(512x256), f32 out
    gemm_split<0><<<dim3(160, 2), 256, 0, stream>>>(Hh, Hl, 512, 512, W2h, W2l, 256, b2,
                                                    V, nullptr, nullptr, 256);
    const unsigned short* vok = VO + (size_t)(k < 3 ? k : 0) * NSEQ * 256;
    step_kernel<<<NSEQ / 4, 256, 0, stream>>>(V, Uh, Ul, ZL, ZN2, vok, k);
    // R1 = relu(U[:,0:256] @ Wr1 + br1)  (20480x256)@(256x512), split out (reuse H)
    gemm_split<2><<<dim3(160, 4), 256, 0, stream>>>(Uh, Ul, 512, 256, Wr1h, Wr1l, 512, br1,
                                                    nullptr, Hh, Hl, 512);
    // out slice = R1 @ Wr2 + br2
    gemm4_mfma<<<160, 256, 0, stream>>>(Hh, Hl, Wr2h, Wr2l, br2, out, k);
  }
}

// Round 5
// 808.936 us; speedup vs baseline: 3.3585x; 1.1426x over previous
//
#include <hip/hip_runtime.h>
#include <cstddef>

#define NSEQ 20480
#define EPSf 1e-7f
#define MAXN 0.99999f
#define MAXN2 (0.99999f * 0.99999f)

typedef __attribute__((ext_vector_type(8))) short bf16x8;
typedef __attribute__((ext_vector_type(4))) float f32x4;

__device__ __forceinline__ unsigned short f2bf(float x) {
  unsigned u = __float_as_uint(x);
  u += 0x7FFF + ((u >> 16) & 1);
  return (unsigned short)(u >> 16);
}
__device__ __forceinline__ float bf2f(unsigned short h) {
  return __uint_as_float(((unsigned)h) << 16);
}

// ---------------- fold transpose: X[b][l][f] (4 arrays) -> XT[ch][b*64+f][l], ch0 = sum ----------------
__global__ __launch_bounds__(256) void fold_transpose(
    const float* __restrict__ t, const float* __restrict__ c,
    const float* __restrict__ f, const float* __restrict__ r,
    float* __restrict__ XT)
{
  __shared__ float tile[4][56][65];
  const int b = blockIdx.x, l0 = blockIdx.y * 56;
  const int tid = threadIdx.x;
  const int fi = tid & 63, lr0 = tid >> 6;
#pragma unroll
  for (int i = 0; i < 14; ++i) {
    int lr = lr0 + i * 4;
    size_t idx = ((size_t)b * 336 + l0 + lr) * 64 + fi;
    tile[0][lr][fi] = t[idx];
    tile[1][lr][fi] = c[idx];
    tile[2][lr][fi] = f[idx];
    tile[3][lr][fi] = r[idx];
  }
  __syncthreads();
#pragma unroll
  for (int ch = 0; ch < 5; ++ch) {
    for (int i = 0; i < 14; ++i) {
      int idx2 = i * 256 + tid;
      int ff = idx2 / 56, ll = idx2 % 56;
      float v;
      if (ch == 0) v = tile[0][ll][ff] + tile[1][ll][ff] + tile[2][ll][ff] + tile[3][ll][ff];
      else v = tile[ch - 1][ll][ff];
      XT[((size_t)ch * 4096 + (b << 6) + ff) * 336 + l0 + ll] = v;
    }
  }
}

// ---------------- weight split+tile: W[k][n] f32 -> Wh/Wl bf16 at [(k>>3)*N + n]*8 + (k&7) ----------------
__global__ __launch_bounds__(256) void conv_weight(
    const float* __restrict__ W, unsigned short* __restrict__ Wh, unsigned short* __restrict__ Wl,
    int K, int N, int Nsrc)
{
  int idx = blockIdx.x * 256 + threadIdx.x;
  if (idx >= K * N) return;
  int k = idx / N, n = idx % N;
  float x = (n < Nsrc) ? W[(size_t)k * Nsrc + n] : 0.f;
  unsigned short h = f2bf(x);
  size_t o = ((size_t)(k >> 3) * N + n) * 8 + (k & 7);
  Wh[o] = h;
  Wl[o] = f2bf(x - bf2f(h));
}

// ---------------- W_emb -> MFMA B-fragment layout: Wg[T][lane][j], k=8*(lane>>4)+j, n=T*16+(lane&15) ----------------
__global__ __launch_bounds__(256) void conv_wemb(
    const float* __restrict__ W_emb, unsigned short* __restrict__ WgH, unsigned short* __restrict__ WgL)
{
  int idx = blockIdx.x * 256 + threadIdx.x;
  if (idx >= 16 * 64 * 8) return;
  int j = idx & 7, ln = (idx >> 3) & 63, T = idx >> 9;
  int k = 8 * (ln >> 4) + j, n = T * 16 + (ln & 15);
  float x = (k < 24) ? W_emb[(size_t)k * 256 + n] : 0.f;
  unsigned short h = f2bf(x);
  WgH[idx] = h;
  WgL[idx] = f2bf(x - bf2f(h));
}

// ---------------- init: MFMA embed + expmap0 + parallel velocity pairs, one WAVE per sequence ----------------
// C-layout: lane (l4,l15) holds segments s = l4*4+r (r=0..3), cols c = T*16+l15 (T=0..15)
__global__ __launch_bounds__(256) void init_kernel(
    const float* __restrict__ XT,
    const unsigned short* __restrict__ WgH, const unsigned short* __restrict__ WgL,
    const float* __restrict__ b_emb,
    unsigned short* __restrict__ Uh, unsigned short* __restrict__ Ul,
    float* __restrict__ ZL, float* __restrict__ ZN2, unsigned short* __restrict__ VO)
{
  __shared__ unsigned short Bsh[2][16][64][8];   // 32 KB, shared by 4 waves
  __shared__ float segs[4][384];
  __shared__ float bsh[256];
  const int tid = threadIdx.x, w = tid >> 6, lane = tid & 63;
  const int l15 = lane & 15, l4 = lane >> 4;
  const int sidx = blockIdx.x * 4 + w;

  {
    const uint4* srcH = (const uint4*)WgH;       // 8192 shorts = 16384 B = 1024 uint4
    uint4* dstH = (uint4*)&Bsh[0][0][0][0];
    for (int i = tid; i < 1024; i += 256) dstH[i] = srcH[i];
    const uint4* srcL = (const uint4*)WgL;
    uint4* dstL = (uint4*)&Bsh[1][0][0][0];
    for (int i = tid; i < 1024; i += 256) dstL[i] = srcL[i];
    bsh[tid] = b_emb[tid];
  }
  const float* src = XT + (size_t)sidx * 336;
  for (int l = lane; l < 336; l += 64) segs[w][l] = src[l];
  for (int l = 336 + lane; l < 384; l += 64) segs[w][l] = 0.f;
  __syncthreads();

  // A fragment: A[row=l15][k=8*l4+j] = seg[l15*24 + 8*l4 + j]; k>=24 (l4==3) -> 0 (B is 0 there too)
  bf16x8 ah, al;
  if (l4 < 3) {
    const float* sp = &segs[w][l15 * 24 + l4 * 8];
#pragma unroll
    for (int j = 0; j < 8; ++j) {
      float v = sp[j];
      unsigned short h = f2bf(v);
      ah[j] = (short)h;
      al[j] = (short)f2bf(v - bf2f(h));
    }
  } else {
#pragma unroll
    for (int j = 0; j < 8; ++j) { ah[j] = 0; al[j] = 0; }
  }

  // 16 N-tiles x 3 split MFMAs
  f32x4 acc[16];
#pragma unroll
  for (int T = 0; T < 16; ++T) acc[T] = (f32x4){0.f, 0.f, 0.f, 0.f};
#pragma unroll
  for (int T = 0; T < 16; ++T) {
    bf16x8 bh = *(const bf16x8*)&Bsh[0][T][lane][0];
    bf16x8 bl = *(const bf16x8*)&Bsh[1][T][lane][0];
    acc[T] = __builtin_amdgcn_mfma_f32_16x16x32_bf16(ah, bh, acc[T], 0, 0, 0);
    acc[T] = __builtin_amdgcn_mfma_f32_16x16x32_bf16(ah, bl, acc[T], 0, 0, 0);
    acc[T] = __builtin_amdgcn_mfma_f32_16x16x32_bf16(al, bh, acc[T], 0, 0, 0);
  }

  // e = tanh(acc + b); norms per segment (f32 butterfly over 16-lane group); expmap0
  float z_[4][16];
  float zn2_[4];
  float ls[4] = {0.f, 0.f, 0.f, 0.f};
#pragma unroll
  for (int T = 0; T < 16; ++T) {
    float b = bsh[T * 16 + l15];
#pragma unroll
    for (int r = 0; r < 4; ++r) {
      float e = tanhf(acc[T][r] + b);
      z_[r][T] = e;
      ls[r] = fmaf(e, e, ls[r]);
    }
  }
#pragma unroll
  for (int m = 1; m < 16; m <<= 1)
#pragma unroll
    for (int r = 0; r < 4; ++r) ls[r] += __shfl_xor(ls[r], m);
#pragma unroll
  for (int r = 0; r < 4; ++r) {
    float vn = sqrtf(fmaxf(ls[r], 1e-14f));
    float tt = tanhf(vn);                 // ||expmap0 pre|| == tanh(||e||) exactly
    bool clip = tt > MAXN;
    float scale = (clip ? MAXN : tt) / vn;
#pragma unroll
    for (int T = 0; T < 16; ++T) z_[r][T] *= scale;
    zn2_[r] = clip ? MAXN2 : tt * tt;
  }

  // cross-group boundary data: next group's reg0 (z and zn2)
  float zsh[16], zn2sh;
#pragma unroll
  for (int T = 0; T < 16; ++T) zsh[T] = __shfl(z_[0][T], (lane + 16) & 63);
  zn2sh = __shfl(zn2_[0], (lane + 16) & 63);

  // velocity pairs: group l4 handles t = 4*l4 + p; groups 0-2: 4 pairs, group 3: 1 pair
  float vel[16];
#pragma unroll
  for (int T = 0; T < 16; ++T) vel[T] = 0.f;
  const float p4c = 0.9f * 0.9f * 0.9f * 0.9f;
  const float p8c = p4c * p4c, p12c = p8c * p4c;
  const float wsum = (1.f - p12c * 0.9f) / 0.1f;
  float wt = ((l4 == 0) ? p12c : (l4 == 1) ? p8c : (l4 == 2) ? p4c : 1.f) / wsum;
  const int npairs = (l4 < 3) ? 4 : 1;
#pragma unroll
  for (int p = 0; p < 4; ++p) {
    if (p < npairs) {
      double sxy = 0.0;
#pragma unroll
      for (int T = 0; T < 16; ++T) {
        float zt1 = (p < 3) ? z_[(p + 1) & 3][T] : zsh[T];
        sxy += (double)z_[p][T] * (double)zt1;
      }
#pragma unroll
      for (int m = 1; m < 16; m <<= 1) sxy += __shfl_xor(sxy, m);   // partners stay in-group
      float x2 = zn2_[p];
      float y2 = (p < 3) ? zn2_[(p + 1) & 3] : zn2sh;
      float xy = (float)sxy;
      float den = fmaxf(1.f - 2.f * xy + x2 * y2, 1e-15f);
      float a2 = (1.f - 2.f * xy + y2) / den;
      float b2c = (1.f - x2) / den;
      float wd[16];
      float sww = 0.f;
#pragma unroll
      for (int T = 0; T < 16; ++T) {
        float zt1 = (p < 3) ? z_[(p + 1) & 3][T] : zsh[T];
        wd[T] = b2c * zt1 - a2 * z_[p][T];
        sww = fmaf(wd[T], wd[T], sww);
      }
#pragma unroll
      for (int m = 1; m < 16; m <<= 1) sww += __shfl_xor(sww, m);
      float wn = sqrtf(fmaxf(sww, 1e-14f));
      float toL = fmaxf(1.f - x2, EPSf);     // = 2/lam at x = z_t
      float vls = toL * atanhf(fminf(wn, 1.f - 1e-6f)) / wn;
#pragma unroll
      for (int T = 0; T < 16; ++T) {
        float vl = vls * wd[T];
        vel[T] = fmaf(wt, vl, vel[T]);
        if (l4 == 0 && p < 3)
          VO[((size_t)p * NSEQ + sidx) * 256 + T * 16 + l15] = f2bf(vl);
      }
      wt *= (1.f / 0.9f);
    }
  }

  // vel all-reduce across the 4 groups
#pragma unroll
  for (int T = 0; T < 16; ++T) {
    vel[T] += __shfl_xor(vel[T], 16);
    vel[T] += __shfl_xor(vel[T], 32);
  }

  // outputs: z13 = group3 reg1
  if (l4 == 3) {
    float ynn = sqrtf(fmaxf(zn2_[1], 1e-14f));
    float gs = atanhf(fminf(ynn, 1.f - 1e-6f)) / ynn;
#pragma unroll
    for (int T = 0; T < 16; ++T) {
      int cidx = T * 16 + l15;
      float g = gs * z_[1][T];
      unsigned short gh = f2bf(g);
      Uh[(size_t)sidx * 512 + cidx] = gh;
      Ul[(size_t)sidx * 512 + cidx] = f2bf(g - bf2f(gh));
      ZL[(size_t)sidx * 256 + cidx] = z_[1][T];
    }
    if (l15 == 0) ZN2[sidx] = zn2_[1];
  }
  if (l4 == 0) {
#pragma unroll
    for (int T = 0; T < 16; ++T) {
      int cidx = T * 16 + l15;
      unsigned short vh = f2bf(vel[T]);
      Uh[(size_t)sidx * 512 + 256 + cidx] = vh;
      Ul[(size_t)sidx * 512 + 256 + cidx] = f2bf(vel[T] - bf2f(vh));
    }
  }
}

// ---------------- split-bf16 MFMA GEMM: C = epi(A @ B + bias), 128x128 tile, BK=32 ----------------
template <int EPI>
__global__ __launch_bounds__(256) void gemm_split(
    const unsigned short* __restrict__ Ah, const unsigned short* __restrict__ Al, int lda, int K,
    const unsigned short* __restrict__ Bh, const unsigned short* __restrict__ Bl, int N,
    const float* __restrict__ bias,
    float* __restrict__ Cf, unsigned short* __restrict__ Ch, unsigned short* __restrict__ Cl, int ldc)
{
  __shared__ unsigned short As[2][4][128][8];
  __shared__ unsigned short Bs[2][4][128][8];
  const int tid = threadIdx.x;
  const int lane = tid & 63, wid = tid >> 6;
  const int wr = wid >> 1, wc = wid & 1;
  const int l15 = lane & 15, l4 = lane >> 4;
  const int row0 = blockIdx.x * 128, col0 = blockIdx.y * 128;

  f32x4 acc[4][4];
#pragma unroll
  for (int i = 0; i < 4; ++i)
#pragma unroll
    for (int j = 0; j < 4; ++j) acc[i][j] = (f32x4){0.f, 0.f, 0.f, 0.f};

  const int sm = tid >> 2, skg = tid & 3;
  const int bn = tid & 127, bkg0 = tid >> 7;

  for (int k0 = 0; k0 < K; k0 += 32) {
    size_t abase = (size_t)(row0 + sm) * lda + k0 + skg * 8;
    *(uint4*)&As[0][skg][sm][0] = *(const uint4*)&Ah[abase];
    *(uint4*)&As[1][skg][sm][0] = *(const uint4*)&Al[abase];
    size_t abase2 = abase + (size_t)64 * lda;
    *(uint4*)&As[0][skg][sm + 64][0] = *(const uint4*)&Ah[abase2];
    *(uint4*)&As[1][skg][sm + 64][0] = *(const uint4*)&Al[abase2];
    size_t bbase = ((size_t)((k0 >> 3) + bkg0) * N + col0 + bn) * 8;
    *(uint4*)&Bs[0][bkg0][bn][0] = *(const uint4*)&Bh[bbase];
    *(uint4*)&Bs[1][bkg0][bn][0] = *(const uint4*)&Bl[bbase];
    size_t bbase2 = bbase + (size_t)2 * N * 8;
    *(uint4*)&Bs[0][bkg0 + 2][bn][0] = *(const uint4*)&Bh[bbase2];
    *(uint4*)&Bs[1][bkg0 + 2][bn][0] = *(const uint4*)&Bl[bbase2];
    __syncthreads();

    bf16x8 fah[4], fal[4], fbh[4], fbl[4];
#pragma unroll
    for (int mi = 0; mi < 4; ++mi) {
      fah[mi] = *(const bf16x8*)&As[0][l4][wr * 64 + mi * 16 + l15][0];
      fal[mi] = *(const bf16x8*)&As[1][l4][wr * 64 + mi * 16 + l15][0];
    }
#pragma unroll
    for (int ni = 0; ni < 4; ++ni) {
      fbh[ni] = *(const bf16x8*)&Bs[0][l4][wc * 64 + ni * 16 + l15][0];
      fbl[ni] = *(const bf16x8*)&Bs[1][l4][wc * 64 + ni * 16 + l15][0];
    }
#pragma unroll
    for (int mi = 0; mi < 4; ++mi)
#pragma unroll
      for (int ni = 0; ni < 4; ++ni) {
        acc[mi][ni] = __builtin_amdgcn_mfma_f32_16x16x32_bf16(fah[mi], fbh[ni], acc[mi][ni], 0, 0, 0);
        acc[mi][ni] = __builtin_amdgcn_mfma_f32_16x16x32_bf16(fah[mi], fbl[ni], acc[mi][ni], 0, 0, 0);
        acc[mi][ni] = __builtin_amdgcn_mfma_f32_16x16x32_bf16(fal[mi], fbh[ni], acc[mi][ni], 0, 0, 0);
      }
    __syncthreads();
  }

#pragma unroll
  for (int mi = 0; mi < 4; ++mi)
#pragma unroll
    for (int ni = 0; ni < 4; ++ni) {
      int cc = col0 + wc * 64 + ni * 16 + l15;
      float bv = bias[cc];
      int rbase = row0 + wr * 64 + mi * 16 + l4 * 4;
#pragma unroll
      for (int r = 0; r < 4; ++r) {
        float v = acc[mi][ni][r] + bv;
        if (EPI == 1) v = tanhf(v);
        else if (EPI == 2) v = fmaxf(v, 0.f);
        if (EPI == 0) {
          Cf[(size_t)(rbase + r) * ldc + cc] = v;
        } else {
          unsigned short h = f2bf(v);
          Ch[(size_t)(rbase + r) * ldc + cc] = h;
          Cl[(size_t)(rbase + r) * ldc + cc] = f2bf(v - bf2f(h));
        }
      }
    }
}

// ---------------- per-sequence step (one WAVE per sequence), f32 scalars ----------------
__device__ __forceinline__ double wave_sum_d(double v) {
#pragma unroll
  for (int off = 32; off > 0; off >>= 1) v += __shfl_xor(v, off);
  return v;
}

__global__ __launch_bounds__(256) void step_kernel(
    const float* __restrict__ V, unsigned short* __restrict__ Uh, unsigned short* __restrict__ Ul,
    float* __restrict__ ZL, float* __restrict__ ZN2, const unsigned short* __restrict__ VOk, int k)
{
  const int tid = threadIdx.x, w = tid >> 6, lane = tid & 63;
  const int sidx = blockIdx.x * 4 + w;

  float x[4], v[4];
#pragma unroll
  for (int j = 0; j < 4; ++j) {
    x[j] = ZL[(size_t)sidx * 256 + lane + 64 * j];
    v[j] = V[(size_t)sidx * 256 + lane + 64 * j];
  }
  float x2 = ZN2[sidx];

  double sxv = 0.0, svv = 0.0;
#pragma unroll
  for (int j = 0; j < 4; ++j) {
    sxv += (double)x[j] * (double)v[j];
    svv += (double)v[j] * (double)v[j];
  }
  float xv = (float)wave_sum_d(sxv);
  float vn2 = (float)wave_sum_d(svv);
  float vn = sqrtf(fmaxf(vn2, 1e-14f));
  float twoOverLam = fmaxf(1.f - x2, EPSf);
  float th = tanhf(vn / twoOverLam);
  float sec_s = th / vn;
  float y2 = th * th;
  float xy = sec_s * xv;
  float den = fmaxf(1.f + 2.f * xy + x2 * y2, 1e-15f);
  float alpha = (1.f + 2.f * xy + y2) / den;
  float beta = (1.f - x2) * sec_s / den;

  float zn[4];
  double snn = 0.0;
#pragma unroll
  for (int j = 0; j < 4; ++j) {
    zn[j] = alpha * x[j] + beta * v[j];
    snn += (double)zn[j] * (double)zn[j];
  }
  float n2 = (float)wave_sum_d(snn);
  float n = sqrtf(fmaxf(n2, 1e-14f));
  bool clip = n > MAXN;
  float scl = clip ? MAXN / n : 1.f;
  float z2 = clip ? MAXN2 : n2;
#pragma unroll
  for (int j = 0; j < 4; ++j) {
    zn[j] *= scl;
    ZL[(size_t)sidx * 256 + lane + 64 * j] = zn[j];
  }
  if (lane == 0) ZN2[sidx] = z2;

  float ynn = sqrtf(fmaxf(z2, 1e-14f));
  float gs = atanhf(fminf(ynn, 1.f - 1e-6f)) / ynn;
#pragma unroll
  for (int j = 0; j < 4; ++j) {
    float g = gs * zn[j];
    unsigned short gh = f2bf(g);
    Uh[(size_t)sidx * 512 + lane + 64 * j] = gh;
    Ul[(size_t)sidx * 512 + lane + 64 * j] = f2bf(g - bf2f(gh));
  }

  if (k < 3) {
    float xy2 = scl * (alpha * x2 + beta * xv);
    float den2 = fmaxf(1.f - 2.f * xy2 + x2 * z2, 1e-15f);
    float a2 = (1.f - 2.f * xy2 + z2) / den2;
    float b2 = (1.f - x2) / den2;
    float wv[4];
    double sww = 0.0;
#pragma unroll
    for (int j = 0; j < 4; ++j) {
      wv[j] = b2 * zn[j] - a2 * x[j];
      sww += (double)wv[j] * (double)wv[j];
    }
    float wn2 = (float)wave_sum_d(sww);
    float wn = sqrtf(fmaxf(wn2, 1e-14f));
    float vls = twoOverLam * atanhf(fminf(wn, 1.f - 1e-6f)) / wn;

    float p12 = 1.f;
#pragma unroll
    for (int i = 0; i < 12; ++i) p12 *= 0.9f;
    float wsum = (1.f - p12 * 0.9f) / 0.1f;
    float w0 = p12 / wsum;
    float w12 = 1.f / wsum;
#pragma unroll
    for (int j = 0; j < 4; ++j) {
      int d = 256 + lane + 64 * j;
      float velold = bf2f(Uh[(size_t)sidx * 512 + d]) + bf2f(Ul[(size_t)sidx * 512 + d]);
      float vdrop = bf2f(VOk[(size_t)sidx * 256 + lane + 64 * j]);
      float velnew = 0.9f * (velold - w0 * vdrop) + w12 * (vls * wv[j]);
      unsigned short vh = f2bf(velnew);
      Uh[(size_t)sidx * 512 + d] = vh;
      Ul[(size_t)sidx * 512 + d] = f2bf(velnew - bf2f(vh));
    }
  }
}

// ---------------- GEMM4 (MFMA): r = R1(20480x512) @ Wr2(512x24->32) + br2, scattered write ----------------
__global__ __launch_bounds__(256) void gemm4_mfma(
    const unsigned short* __restrict__ Ah, const unsigned short* __restrict__ Al,
    const unsigned short* __restrict__ Bh, const unsigned short* __restrict__ Bl,
    const float* __restrict__ br2, float* __restrict__ out, int step)
{
  __shared__ unsigned short As[2][4][128][8];
  __shared__ unsigned short Bs[2][4][32][8];
  const int tid = threadIdx.x, lane = tid & 63, wid = tid >> 6;
  const int l15 = lane & 15, l4 = lane >> 4;
  const int row0 = blockIdx.x * 128;

  f32x4 acc[2][2];
#pragma unroll
  for (int i = 0; i < 2; ++i)
#pragma unroll
    for (int j = 0; j < 2; ++j) acc[i][j] = (f32x4){0.f, 0.f, 0.f, 0.f};

  const int sm = tid >> 2, skg = tid & 3;
  const int bplane = tid >> 7, bc = tid & 127, bkg = bc >> 5, bnn = bc & 31;
  const unsigned short* Bp = bplane ? Bl : Bh;

  for (int k0 = 0; k0 < 512; k0 += 32) {
    size_t abase = (size_t)(row0 + sm) * 512 + k0 + skg * 8;
    *(uint4*)&As[0][skg][sm][0] = *(const uint4*)&Ah[abase];
    *(uint4*)&As[1][skg][sm][0] = *(const uint4*)&Al[abase];
    size_t abase2 = abase + (size_t)64 * 512;
    *(uint4*)&As[0][skg][sm + 64][0] = *(const uint4*)&Ah[abase2];
    *(uint4*)&As[1][skg][sm + 64][0] = *(const uint4*)&Al[abase2];
    size_t bbase = ((size_t)((k0 >> 3) + bkg) * 32 + bnn) * 8;
    *(uint4*)&Bs[bplane][bkg][bnn][0] = *(const uint4*)&Bp[bbase];
    __syncthreads();

    bf16x8 fah[2], fal[2], fbh[2], fbl[2];
#pragma unroll
    for (int mi = 0; mi < 2; ++mi) {
      fah[mi] = *(const bf16x8*)&As[0][l4][wid * 32 + mi * 16 + l15][0];
      fal[mi] = *(const bf16x8*)&As[1][l4][wid * 32 + mi * 16 + l15][0];
    }
#pragma unroll
    for (int ni = 0; ni < 2; ++ni) {
      fbh[ni] = *(const bf16x8*)&Bs[0][l4][ni * 16 + l15][0];
      fbl[ni] = *(const bf16x8*)&Bs[1][l4][ni * 16 + l15][0];
    }
#pragma unroll
    for (int mi = 0; mi < 2; ++mi)
#pragma unroll
      for (int ni = 0; ni < 2; ++ni) {
        acc[mi][ni] = __builtin_amdgcn_mfma_f32_16x16x32_bf16(fah[mi], fbh[ni], acc[mi][ni], 0, 0, 0);
        acc[mi][ni] = __builtin_amdgcn_mfma_f32_16x16x32_bf16(fah[mi], fbl[ni], acc[mi][ni], 0, 0, 0);
        acc[mi][ni] = __builtin_amdgcn_mfma_f32_16x16x32_bf16(fal[mi], fbh[ni], acc[mi][ni], 0, 0, 0);
      }
    __syncthreads();
  }

#pragma unroll
  for (int mi = 0; mi < 2; ++mi)
#pragma unroll
    for (int ni = 0; ni < 2; ++ni) {
      int j = ni * 16 + l15;
      if (j < 24) {
        float bv = br2[j];
#pragma unroll
        for (int r = 0; r < 4; ++r) {
          int row = row0 + wid * 32 + mi * 16 + l4 * 4 + r;
          int c = row >> 12, bf = row & 4095, b = bf >> 6, f = bf & 63;
          size_t base = (((size_t)(c * 64 + b) * 96) + (size_t)step * 24 + j) * 64 + f;
          out[base] = acc[mi][ni][r] + bv;
        }
      }
    }
}

extern "C" void kernel_launch(void* const* d_in, const int* in_sizes, int n_in,
                              void* d_out, int out_size, void* d_ws, size_t ws_size,
                              hipStream_t stream)
{
  const float* trend  = (const float*)d_in[0];
  const float* coarse = (const float*)d_in[1];
  const float* fine   = (const float*)d_in[2];
  const float* resid  = (const float*)d_in[3];
  const float* W_emb  = (const float*)d_in[4];
  const float* b_emb  = (const float*)d_in[5];
  const float* W1  = (const float*)d_in[6];
  const float* b1  = (const float*)d_in[7];
  const float* W2  = (const float*)d_in[8];
  const float* b2  = (const float*)d_in[9];
  const float* Wr1 = (const float*)d_in[10];
  const float* br1 = (const float*)d_in[11];
  const float* Wr2 = (const float*)d_in[12];
  const float* br2 = (const float*)d_in[13];
  float* out = (float*)d_out;

  char* p = (char*)d_ws;
  size_t off = 0;
  auto alloc = [&](size_t bytes) -> void* {
    void* r = p + off;
    off = (off + bytes + 255) & ~(size_t)255;
    return r;
  };
  unsigned short* Uh = (unsigned short*)alloc((size_t)NSEQ * 512 * 2);
  unsigned short* Ul = (unsigned short*)alloc((size_t)NSEQ * 512 * 2);
  unsigned short* Hh = (unsigned short*)alloc((size_t)NSEQ * 512 * 2);
  unsigned short* Hl = (unsigned short*)alloc((size_t)NSEQ * 512 * 2);
  float* V   = (float*)alloc((size_t)NSEQ * 256 * 4);
  float* ZL  = (float*)alloc((size_t)NSEQ * 256 * 4);
  float* ZN2 = (float*)alloc((size_t)NSEQ * 4);
  unsigned short* VO = (unsigned short*)alloc((size_t)3 * NSEQ * 256 * 2);
  float* XT  = (float*)alloc((size_t)5 * 4096 * 336 * 4);
  unsigned short* W1h = (unsigned short*)alloc((size_t)512 * 512 * 2);
  unsigned short* W1l = (unsigned short*)alloc((size_t)512 * 512 * 2);
  unsigned short* W2h = (unsigned short*)alloc((size_t)512 * 256 * 2);
  unsigned short* W2l = (unsigned short*)alloc((size_t)512 * 256 * 2);
  unsigned short* Wr1h = (unsigned short*)alloc((size_t)256 * 512 * 2);
  unsigned short* Wr1l = (unsigned short*)alloc((size_t)256 * 512 * 2);
  unsigned short* Wr2h = (unsigned short*)alloc((size_t)512 * 32 * 2);
  unsigned short* Wr2l = (unsigned short*)alloc((size_t)512 * 32 * 2);
  unsigned short* WgH = (unsigned short*)alloc((size_t)16 * 64 * 8 * 2);
  unsigned short* WgL = (unsigned short*)alloc((size_t)16 * 64 * 8 * 2);

  fold_transpose<<<dim3(64, 6), 256, 0, stream>>>(trend, coarse, fine, resid, XT);
  conv_weight<<<(512 * 512 + 255) / 256, 256, 0, stream>>>(W1, W1h, W1l, 512, 512, 512);
  conv_weight<<<(512 * 256 + 255) / 256, 256, 0, stream>>>(W2, W2h, W2l, 512, 256, 256);
  conv_weight<<<(256 * 512 + 255) / 256, 256, 0, stream>>>(Wr1, Wr1h, Wr1l, 256, 512, 512);
  conv_weight<<<(512 * 32 + 255) / 256, 256, 0, stream>>>(Wr2, Wr2h, Wr2l, 512, 32, 24);
  conv_wemb<<<32, 256, 0, stream>>>(W_emb, WgH, WgL);
  init_kernel<<<NSEQ / 4, 256, 0, stream>>>(XT, WgH, WgL, b_emb, Uh, Ul, ZL, ZN2, VO);

  for (int k = 0; k < 4; ++k) {
    gemm_split<1><<<dim3(160, 4), 256, 0, stream>>>(Uh, Ul, 512, 512, W1h, W1l, 512, b1,
                                                    nullptr, Hh, Hl, 512);
    gemm_split<0><<<dim3(160, 2), 256, 0, stream>>>(Hh, Hl, 512, 512, W2h, W2l, 256, b2,
                                                    V, nullptr, nullptr, 256);
    const unsigned short* vok = VO + (size_t)(k < 3 ? k : 0) * NSEQ * 256;
    step_kernel<<<NSEQ / 4, 256, 0, stream>>>(V, Uh, Ul, ZL, ZN2, vok, k);
    gemm_split<2><<<dim3(160, 4), 256, 0, stream>>>(Uh, Ul, 512, 256, Wr1h, Wr1l, 512, br1,
                                                    nullptr, Hh, Hl, 512);
    gemm4_mfma<<<160, 256, 0, stream>>>(Hh, Hl, Wr2h, Wr2l, br2, out, k);
  }
}